// Round 2
// baseline (255.667 us; speedup 1.0000x reference)
//
#include <hip/hip_runtime.h>
#include <hip/hip_bf16.h>

// ---------------------------------------------------------------------------
// GraphExpert: per-node expert MLPs (16 nodes, 2048 batch, 512 hid) + gating.
// All global I/O is fp32 (reference dtype); MFMA compute in bf16.
//   h    = relu(graphs @ W1 + b1)          per node: 2048x512 @ 512x512
//   outs = h @ W2 + b2                     per node: 2048x512 @ 512x512
//   combined[b, 32n+m] = sum_j probs[b,j] * outs[b,n,16m+j]   (raw-reshape combine)
//   probs = softmax(graphs_flat @ Wg + bg)
// Outputs (fp32, concat flat): combined (2048x512), expert_probs (2048x16)
// ---------------------------------------------------------------------------

typedef __attribute__((ext_vector_type(8))) short bf16x8;   // 8 bf16 = 4 VGPRs
typedef __attribute__((ext_vector_type(4))) float f32x4;    // MFMA C/D frag

// workspace layout (bytes)
#define OFF_W1T  (0u)          // bf16 [16][512][512]  (8 MB)
#define OFF_W2T  (8388608u)    // bf16 [16][512][512]  (8 MB)
#define OFF_H    (16777216u)   // bf16 [2048][16][512] (32 MB)
#define OFF_PART (50331648u)   // fp32 [16][2048][16]  (2 MB)
#define OFF_PROB (52428800u)   // fp32 [2048][16]      (128 KB)

__device__ __forceinline__ void gl2lds16(const void* g, void* l) {
  __builtin_amdgcn_global_load_lds(
      (const __attribute__((address_space(1))) void*)g,
      (__attribute__((address_space(3))) void*)l, 16, 0, 0);
}

// convert 16 contiguous fp32 -> 16 bf16 into LDS (two 16B stores)
__device__ __forceinline__ void cvt16(const float* __restrict__ src, char* dst) {
  float f[16];
  *(float4*)(f + 0)  = *(const float4*)(src + 0);
  *(float4*)(f + 4)  = *(const float4*)(src + 4);
  *(float4*)(f + 8)  = *(const float4*)(src + 8);
  *(float4*)(f + 12) = *(const float4*)(src + 12);
  __hip_bfloat16 t[16];
#pragma unroll
  for (int e = 0; e < 16; e++) t[e] = __float2bfloat16(f[e]);
  *(bf16x8*)dst        = *(const bf16x8*)t;
  *(bf16x8*)(dst + 16) = *(const bf16x8*)(t + 8);
}

// ------------- weight transpose + cvt: Wt[n][h][k] = bf16(W[n][k][h]) -------
__global__ void transpose_kernel(const float* __restrict__ W1,
                                 const float* __restrict__ W2,
                                 __hip_bfloat16* __restrict__ W1t,
                                 __hip_bfloat16* __restrict__ W2t) {
  __shared__ __hip_bfloat16 tile[32][33];
  const int n = blockIdx.z & 15;
  const float* src = (blockIdx.z >> 4) ? W2 : W1;
  __hip_bfloat16* dst = (blockIdx.z >> 4) ? W2t : W1t;
  src += (size_t)n * 262144;
  dst += (size_t)n * 262144;
  const int h0 = blockIdx.x * 32, k0 = blockIdx.y * 32;
  const int tx = threadIdx.x, ty = threadIdx.y; // 32 x 8
#pragma unroll
  for (int i = 0; i < 32; i += 8)
    tile[ty + i][tx] = __float2bfloat16(src[(size_t)(k0 + ty + i) * 512 + h0 + tx]);
  __syncthreads();
#pragma unroll
  for (int i = 0; i < 32; i += 8)
    dst[(size_t)(h0 + ty + i) * 512 + k0 + tx] = tile[tx][ty + i];
}

// ---------------- gating partials: partial[n][b][j] = graphs_n @ Wg_n -------
__global__ __launch_bounds__(256) void gating_kernel(
    const float* __restrict__ graphs,
    const float* __restrict__ Wg,
    float* __restrict__ partial) {
  __shared__ char smem[8192 + 16 * 1040]; // A tile 128x32 bf16 + WgT 16 x 520(pad)
  const int tid = threadIdx.x, lane = tid & 63, wave = tid >> 6;
  const int rb = blockIdx.x; // 0..15 row blocks of 128
  const int n  = blockIdx.y; // 0..15 nodes
  const int q = lane >> 4, l15 = lane & 15;

  // stage Wg slice transposed+converted: Bt[j][k] = bf16(Wg[n*512+k][j])
  char* Bt = smem + 8192;
#pragma unroll
  for (int i = 0; i < 2; i++) {
    int k = i * 256 + tid;
    const float* wr = Wg + (size_t)(n * 512 + k) * 16;
    float f[16];
    *(float4*)(f + 0)  = *(const float4*)(wr + 0);
    *(float4*)(f + 4)  = *(const float4*)(wr + 4);
    *(float4*)(f + 8)  = *(const float4*)(wr + 8);
    *(float4*)(f + 12) = *(const float4*)(wr + 12);
#pragma unroll
    for (int j = 0; j < 16; j++)
      *(__hip_bfloat16*)(Bt + j * 1040 + k * 2) = __float2bfloat16(f[j]);
  }

  const float* Ag = graphs + (size_t)(rb * 128) * 8192 + n * 512;
  const int arow = tid >> 1, akh = (tid & 1) * 16;

  f32x4 acc[2] = {};
  for (int k0 = 0; k0 < 512; k0 += 32) {
    cvt16(Ag + (size_t)arow * 8192 + k0 + akh, smem + arow * 64 + akh * 2);
    __syncthreads();
    bf16x8 bv = *(const bf16x8*)(Bt + l15 * 1040 + (k0 + q * 8) * 2);
#pragma unroll
    for (int im = 0; im < 2; im++) {
      bf16x8 av = *(const bf16x8*)(smem + (wave * 32 + im * 16 + l15) * 64 + q * 16);
      acc[im] = __builtin_amdgcn_mfma_f32_16x16x32_bf16(av, bv, acc[im], 0, 0, 0);
    }
    __syncthreads();
  }
#pragma unroll
  for (int im = 0; im < 2; im++)
#pragma unroll
    for (int r = 0; r < 4; r++) {
      int row = rb * 128 + wave * 32 + im * 16 + q * 4 + r;
      partial[((size_t)n * 2048 + row) * 16 + l15] = acc[im][r];
    }
}

// ---------------- softmax: probs fp32 (ws) + expert_probs fp32 (out) --------
__global__ void softmax_kernel(const float* __restrict__ partial,
                               const float* __restrict__ bg,
                               float* __restrict__ probs,
                               float* __restrict__ probs_out) {
  const int r = blockIdx.x * 256 + threadIdx.x; // 0..2047
  float s[16];
#pragma unroll
  for (int j = 0; j < 16; j++) s[j] = 0.f;
  for (int nn = 0; nn < 16; nn++) {
    const float4* p = (const float4*)(partial + ((size_t)nn * 2048 + r) * 16);
#pragma unroll
    for (int c = 0; c < 4; c++) {
      float4 v = p[c];
      s[c * 4 + 0] += v.x; s[c * 4 + 1] += v.y;
      s[c * 4 + 2] += v.z; s[c * 4 + 3] += v.w;
    }
  }
  float mx = -1e30f;
#pragma unroll
  for (int j = 0; j < 16; j++) { s[j] += bg[j]; mx = fmaxf(mx, s[j]); }
  float sum = 0.f;
#pragma unroll
  for (int j = 0; j < 16; j++) { s[j] = __expf(s[j] - mx); sum += s[j]; }
  float inv = 1.f / sum;
#pragma unroll
  for (int j = 0; j < 16; j++) s[j] *= inv;
  float4* pw = (float4*)(probs + (size_t)r * 16);
  float4* ow = (float4*)(probs_out + (size_t)r * 16);
#pragma unroll
  for (int c = 0; c < 4; c++) {
    float4 v = make_float4(s[c*4], s[c*4+1], s[c*4+2], s[c*4+3]);
    pw[c] = v; ow[c] = v;
  }
}

// ---------------- GEMM1: h = bf16(relu(graphs @ W1 + b1)) -------------------
__global__ __launch_bounds__(256) void gemm1_kernel(
    const float* __restrict__ graphs,
    const __hip_bfloat16* __restrict__ W1t,
    const float* __restrict__ b1,
    __hip_bfloat16* __restrict__ h) {
  __shared__ char smem[36864]; // K-loop: A 8K + B 8K; epilogue: 4 x 64x72 bf16
  const int tid = threadIdx.x, lane = tid & 63, wave = tid >> 6;
  const int nblk = blockIdx.x, mblk = blockIdx.y, n = blockIdx.z;
  const int wm = (wave >> 1) * 64, wn = (wave & 1) * 64;
  const int q = lane >> 4, l15 = lane & 15;
  const int srow = lane >> 2, scol = (lane & 3) * 8;
  const int arow = tid >> 1, akh = (tid & 1) * 16;

  const float* Ag = graphs + (size_t)(mblk * 128) * 8192 + n * 512;
  const __hip_bfloat16* Bg = W1t + (size_t)n * 262144 + (size_t)(nblk * 128) * 512;

  f32x4 acc[4][4] = {};
  for (int k0 = 0; k0 < 512; k0 += 32) {
    cvt16(Ag + (size_t)arow * 8192 + k0 + akh, smem + arow * 64 + akh * 2);
#pragma unroll
    for (int rep = 0; rep < 2; rep++) {
      int row = wave * 32 + rep * 16 + srow;
      gl2lds16(Bg + (size_t)row * 512 + k0 + scol, smem + 8192 + row * 64 + (lane & 3) * 16);
    }
    __syncthreads();
    bf16x8 av[4], bv[4];
#pragma unroll
    for (int im = 0; im < 4; im++)
      av[im] = *(const bf16x8*)(smem + (wm + im * 16 + l15) * 64 + q * 16);
#pragma unroll
    for (int in = 0; in < 4; in++)
      bv[in] = *(const bf16x8*)(smem + 8192 + (wn + in * 16 + l15) * 64 + q * 16);
#pragma unroll
    for (int im = 0; im < 4; im++)
#pragma unroll
      for (int in = 0; in < 4; in++)
        acc[im][in] = __builtin_amdgcn_mfma_f32_16x16x32_bf16(av[im], bv[in], acc[im][in], 0, 0, 0);
    __syncthreads();
  }

  // epilogue: bias + relu, repack via LDS (row stride 72 elems = 144 B), coalesced store
  float bias[4];
#pragma unroll
  for (int in = 0; in < 4; in++)
    bias[in] = b1[n * 512 + nblk * 128 + wn + in * 16 + l15];
  char* epi = smem + wave * 9216;
#pragma unroll
  for (int im = 0; im < 4; im++)
#pragma unroll
    for (int in = 0; in < 4; in++)
#pragma unroll
      for (int r = 0; r < 4; r++) {
        float v = acc[im][in][r] + bias[in];
        v = fmaxf(v, 0.f);
        int rl = im * 16 + q * 4 + r;
        int cl = in * 16 + l15;
        *(__hip_bfloat16*)(epi + rl * 144 + cl * 2) = __float2bfloat16(v);
      }
  __syncthreads();
  __hip_bfloat16* Hg = h + (size_t)(mblk * 128 + wm) * 8192 + n * 512 + nblk * 128 + wn;
#pragma unroll
  for (int it = 0; it < 8; it++) {
    int rl = it * 8 + (lane >> 3);
    int cl = (lane & 7) * 8;
    bf16x8 v = *(const bf16x8*)(epi + rl * 144 + cl * 2);
    *(bf16x8*)(Hg + (size_t)rl * 8192 + cl) = v;
  }
}

// ---------------- GEMM2 + weighted combine (fp32 out) -----------------------
__global__ __launch_bounds__(256) void gemm2_kernel(
    const __hip_bfloat16* __restrict__ hbuf,
    const __hip_bfloat16* __restrict__ W2t,
    const float* __restrict__ b2,
    const float* __restrict__ probs,
    float* __restrict__ out) {
  __shared__ char smem[16384];
  const int tid = threadIdx.x, lane = tid & 63, wave = tid >> 6;
  const int nblk = blockIdx.x, mblk = blockIdx.y, n = blockIdx.z;
  const int wm = (wave >> 1) * 64, wn = (wave & 1) * 64;
  const int q = lane >> 4, l15 = lane & 15;
  const int srow = lane >> 2, scol = (lane & 3) * 8;

  const __hip_bfloat16* Ag = hbuf + (size_t)(mblk * 128) * 8192 + n * 512;
  const __hip_bfloat16* Bg = W2t + (size_t)n * 262144 + (size_t)(nblk * 128) * 512;

  f32x4 acc[4][4] = {};
  for (int k0 = 0; k0 < 512; k0 += 32) {
#pragma unroll
    for (int rep = 0; rep < 2; rep++) {
      int row = wave * 32 + rep * 16 + srow;
      gl2lds16(Ag + (size_t)row * 8192 + k0 + scol, smem + row * 64 + (lane & 3) * 16);
      gl2lds16(Bg + (size_t)row * 512 + k0 + scol, smem + 8192 + row * 64 + (lane & 3) * 16);
    }
    __syncthreads();
    bf16x8 av[4], bv[4];
#pragma unroll
    for (int im = 0; im < 4; im++)
      av[im] = *(const bf16x8*)(smem + (wm + im * 16 + l15) * 64 + q * 16);
#pragma unroll
    for (int in = 0; in < 4; in++)
      bv[in] = *(const bf16x8*)(smem + 8192 + (wn + in * 16 + l15) * 64 + q * 16);
#pragma unroll
    for (int im = 0; im < 4; im++)
#pragma unroll
      for (int in = 0; in < 4; in++)
        acc[im][in] = __builtin_amdgcn_mfma_f32_16x16x32_bf16(av[im], bv[in], acc[im][in], 0, 0, 0);
    __syncthreads();
  }

  // epilogue: (outs + b2) * probs, reduce over 16 cols of each tile via shfl,
  // combined[b, 32n + nblk*8 + (wn>>4) + in]
  float bias[4];
#pragma unroll
  for (int in = 0; in < 4; in++)
    bias[in] = b2[n * 512 + nblk * 128 + wn + in * 16 + l15];
  float* comb = (float*)smem; // [128][8] fp32
#pragma unroll
  for (int im = 0; im < 4; im++)
#pragma unroll
    for (int r = 0; r < 4; r++) {
      int rl = wm + im * 16 + q * 4 + r; // block-local row 0..127
      float pv = probs[(size_t)(mblk * 128 + rl) * 16 + l15];
#pragma unroll
      for (int in = 0; in < 4; in++) {
        float v = (acc[im][in][r] + bias[in]) * pv;
        v += __shfl_xor(v, 1);
        v += __shfl_xor(v, 2);
        v += __shfl_xor(v, 4);
        v += __shfl_xor(v, 8);
        if (l15 == 0) comb[rl * 8 + (wn >> 4) + in] = v;
      }
    }
  __syncthreads();
  if (tid < 128) {
    float4 v0 = *(const float4*)(comb + tid * 8);
    float4 v1 = *(const float4*)(comb + tid * 8 + 4);
    float* orow = out + (size_t)(mblk * 128 + tid) * 512 + n * 32 + nblk * 8;
    *(float4*)orow = v0;
    *(float4*)(orow + 4) = v1;
  }
}

// ---------------------------------------------------------------------------
extern "C" void kernel_launch(void* const* d_in, const int* in_sizes, int n_in,
                              void* d_out, int out_size, void* d_ws, size_t ws_size,
                              hipStream_t stream) {
  const float* graphs = (const float*)d_in[0];
  const float* W1 = (const float*)d_in[1];
  const float* b1 = (const float*)d_in[2];
  const float* W2 = (const float*)d_in[3];
  const float* b2 = (const float*)d_in[4];
  const float* Wg = (const float*)d_in[5];
  const float* bg = (const float*)d_in[6];
  float* out = (float*)d_out;

  char* ws = (char*)d_ws;
  __hip_bfloat16* W1t = (__hip_bfloat16*)(ws + OFF_W1T);
  __hip_bfloat16* W2t = (__hip_bfloat16*)(ws + OFF_W2T);
  __hip_bfloat16* hb  = (__hip_bfloat16*)(ws + OFF_H);
  float* partial = (float*)(ws + OFF_PART);
  float* probs   = (float*)(ws + OFF_PROB);

  transpose_kernel<<<dim3(16, 16, 32), dim3(32, 8), 0, stream>>>(W1, W2, W1t, W2t);
  gating_kernel<<<dim3(16, 16), 256, 0, stream>>>(graphs, Wg, partial);
  softmax_kernel<<<8, 256, 0, stream>>>(partial, bg, probs, out + 2048 * 512);
  gemm1_kernel<<<dim3(4, 16, 16), 256, 0, stream>>>(graphs, W1t, b1, hb);
  gemm2_kernel<<<dim3(4, 16, 16), 256, 0, stream>>>(hb, W2t, b2, probs, out);
}

// Round 4
// 220.070 us; speedup vs baseline: 1.1618x; 1.1618x over previous
//
#include <hip/hip_runtime.h>
#include <hip/hip_bf16.h>

// ---------------------------------------------------------------------------
// GraphExpert: per-node expert MLPs (16 nodes, 2048 batch, 512 hid) + gating.
// fp32 global I/O, bf16 MFMA compute.
// NOTE: workspace kept within the R2-proven 52.56 MB envelope (R3's 86 MB
// layout is the prime suspect for its garbage output: ws_size is unknown,
// only >= 52.56 MB is proven).
// ---------------------------------------------------------------------------

typedef __attribute__((ext_vector_type(8))) short bf16x8;   // 8 bf16 = 4 VGPRs
typedef __attribute__((ext_vector_type(4))) float f32x4;    // MFMA C/D frag

// workspace layout (bytes) — identical to R2 (proven safe)
#define OFF_W1T  (0u)          // bf16 [16][512][512]  (8 MB)
#define OFF_W2T  (8388608u)    // bf16 [16][512][512]  (8 MB)
#define OFF_H    (16777216u)   // bf16 [2048][16][512] (33.55 MB)
#define OFF_PART (50331648u)   // fp32 [16][2048][16]  (2 MB)
#define OFF_PROB (52428800u)   // fp32 [2048][16]      (128 KB)

__device__ __forceinline__ void gl2lds16(const void* g, void* l) {
  __builtin_amdgcn_global_load_lds(
      (const __attribute__((address_space(1))) void*)g,
      (__attribute__((address_space(3))) void*)l, 16, 0, 0);
}

__device__ __forceinline__ void cvt16v(const float* __restrict__ src,
                                       bf16x8& lo, bf16x8& hi) {
  float f[16];
  *(float4*)(f + 0)  = *(const float4*)(src + 0);
  *(float4*)(f + 4)  = *(const float4*)(src + 4);
  *(float4*)(f + 8)  = *(const float4*)(src + 8);
  *(float4*)(f + 12) = *(const float4*)(src + 12);
  __hip_bfloat16 t[16];
#pragma unroll
  for (int e = 0; e < 16; e++) t[e] = __float2bfloat16(f[e]);
  lo = *(const bf16x8*)t;
  hi = *(const bf16x8*)(t + 8);
}

// ------------- weight transpose + cvt: Wt[n][h][k] = bf16(W[n][k][h]) -------
__global__ void transpose_kernel(const float* __restrict__ W1,
                                 const float* __restrict__ W2,
                                 __hip_bfloat16* __restrict__ W1t,
                                 __hip_bfloat16* __restrict__ W2t) {
  __shared__ __hip_bfloat16 tile[32][33];
  const int n = blockIdx.z & 15;
  const float* src = (blockIdx.z >> 4) ? W2 : W1;
  __hip_bfloat16* dst = (blockIdx.z >> 4) ? W2t : W1t;
  src += (size_t)n * 262144;
  dst += (size_t)n * 262144;
  const int h0 = blockIdx.x * 32, k0 = blockIdx.y * 32;
  const int tx = threadIdx.x, ty = threadIdx.y; // 32 x 8
#pragma unroll
  for (int i = 0; i < 32; i += 8)
    tile[ty + i][tx] = __float2bfloat16(src[(size_t)(k0 + ty + i) * 512 + h0 + tx]);
  __syncthreads();
#pragma unroll
  for (int i = 0; i < 32; i += 8)
    dst[(size_t)(h0 + ty + i) * 512 + k0 + tx] = tile[tx][ty + i];
}

// ---- gating: partial[n][b][j] = graphs_n @ Wg_n ----------------------------
// wave-autonomous k-split: wave w handles k in [w*128, w*128+128), no barriers
// in the hot loop; one cross-wave LDS reduction at the end.
__global__ __launch_bounds__(256) void gating_kernel(
    const float* __restrict__ graphs,
    const float* __restrict__ Wg,
    float* __restrict__ partial) {
  __shared__ char smem[24832]; // [0,8192): per-wave A buf 32x32 bf16 (later red
                               // [wave][32][16] fp32); [8192,..): Bt 16x520 bf16
  const int tid = threadIdx.x, lane = tid & 63, wave = tid >> 6;
  const int bid = blockIdx.x;
  const int n = bid & 15, rb = bid >> 4; // 64 row-blocks of 32 rows
  const int q = lane >> 4, l15 = lane & 15;

  // build Bt[j][k] = bf16(Wg[(n*512+k)*16 + j]), row stride 520 elems (1040 B)
  char* Bt = smem + 8192;
#pragma unroll
  for (int i = 0; i < 2; i++) {
    int k = i * 256 + tid;
    const float* wr_ = Wg + (size_t)(n * 512 + k) * 16;
    float f[16];
    *(float4*)(f + 0)  = *(const float4*)(wr_ + 0);
    *(float4*)(f + 4)  = *(const float4*)(wr_ + 4);
    *(float4*)(f + 8)  = *(const float4*)(wr_ + 8);
    *(float4*)(f + 12) = *(const float4*)(wr_ + 12);
#pragma unroll
    for (int j = 0; j < 16; j++)
      *(__hip_bfloat16*)(Bt + j * 1040 + k * 2) = __float2bfloat16(f[j]);
  }
  __syncthreads();

  const int arow = lane >> 1, ahalf = (lane & 1) * 16;
  const float* Ag = graphs + (size_t)(rb * 32) * 8192 + n * 512 + wave * 128;
  char* Aw = smem + wave * 2048; // 32 rows x 64 B

  f32x4 acc[2] = {};
  for (int ks = 0; ks < 4; ks++) {
    bf16x8 lo, hi;
    cvt16v(Ag + (size_t)arow * 8192 + ks * 32 + ahalf, lo, hi);
    char* d = Aw + arow * 64 + ahalf * 2;
    *(bf16x8*)d = lo;
    *(bf16x8*)(d + 16) = hi;
    // wave-local LDS: DS ops in-order per wave, compiler inserts lgkmcnt waits
    bf16x8 bv = *(const bf16x8*)(Bt + l15 * 1040 + (wave * 128 + ks * 32 + q * 8) * 2);
#pragma unroll
    for (int im = 0; im < 2; im++) {
      bf16x8 av = *(const bf16x8*)(Aw + (im * 16 + l15) * 64 + q * 16);
      acc[im] = __builtin_amdgcn_mfma_f32_16x16x32_bf16(av, bv, acc[im], 0, 0, 0);
    }
  }
  // dump per-wave partials (reuse own A region as red[wave][32][16] fp32)
#pragma unroll
  for (int im = 0; im < 2; im++)
#pragma unroll
    for (int r = 0; r < 4; r++)
      *(float*)(smem + wave * 2048 + (im * 16 + q * 4 + r) * 64 + l15 * 4) = acc[im][r];
  __syncthreads();
  // sum over the 4 waves' k-quarters: 512 cells, 2 per thread
#pragma unroll
  for (int i = 0; i < 2; i++) {
    int c = i * 256 + tid;
    int rrow = c >> 4, j = c & 15;
    float s = 0.f;
#pragma unroll
    for (int w = 0; w < 4; w++) s += *(const float*)(smem + w * 2048 + rrow * 64 + j * 4);
    partial[((size_t)n * 2048 + rb * 32 + rrow) * 16 + j] = s;
  }
}

// ---------------- softmax: probs fp32 (ws) + expert_probs fp32 (out) --------
__global__ void softmax_kernel(const float* __restrict__ partial,
                               const float* __restrict__ bg,
                               float* __restrict__ probs,
                               float* __restrict__ probs_out) {
  const int r = blockIdx.x * 256 + threadIdx.x; // 0..2047
  float s[16];
#pragma unroll
  for (int j = 0; j < 16; j++) s[j] = 0.f;
  for (int nn = 0; nn < 16; nn++) {
    const float4* p = (const float4*)(partial + ((size_t)nn * 2048 + r) * 16);
#pragma unroll
    for (int c = 0; c < 4; c++) {
      float4 v = p[c];
      s[c * 4 + 0] += v.x; s[c * 4 + 1] += v.y;
      s[c * 4 + 2] += v.z; s[c * 4 + 3] += v.w;
    }
  }
  float mx = -1e30f;
#pragma unroll
  for (int j = 0; j < 16; j++) { s[j] += bg[j]; mx = fmaxf(mx, s[j]); }
  float sum = 0.f;
#pragma unroll
  for (int j = 0; j < 16; j++) { s[j] = __expf(s[j] - mx); sum += s[j]; }
  float inv = 1.f / sum;
#pragma unroll
  for (int j = 0; j < 16; j++) s[j] *= inv;
  float4* pw = (float4*)(probs + (size_t)r * 16);
  float4* ow = (float4*)(probs_out + (size_t)r * 16);
#pragma unroll
  for (int c = 0; c < 4; c++) {
    float4 v = make_float4(s[c*4], s[c*4+1], s[c*4+2], s[c*4+3]);
    pw[c] = v; ow[c] = v;
  }
}

// block-id remap: the 4 nblk siblings sharing one A-strip sit at bids
// b, b+8, b+16, b+24 (same bid%8 -> same XCD if dispatch is round-robin),
// so re-reads of the A strip hit that XCD's L2.
__device__ __forceinline__ void decode_bid(int bid, int& nblk, int& mblk, int& n) {
  int x8 = bid & 7;
  nblk = (bid >> 3) & 3;
  int pair = (bid >> 5) * 8 + x8; // 0..255
  mblk = pair >> 4;
  n = pair & 15;
}

// ---------------- GEMM1: h = bf16(relu(graphs @ W1t + b1)) ------------------
// BK=64; XOR-swizzled LDS: LDS[row][slot s] = Gchunk[s ^ (row&7)] (16B chunks)
__global__ __launch_bounds__(256, 4) void gemm1_kernel(
    const float* __restrict__ graphs,
    const __hip_bfloat16* __restrict__ W1t,
    const float* __restrict__ b1,
    __hip_bfloat16* __restrict__ h) {
  __shared__ char smem[36864]; // A 16K @0, B 16K @16384; epilogue 4x9216
  const int tid = threadIdx.x, lane = tid & 63, wave = tid >> 6;
  int nblk, mblk, n;
  decode_bid(blockIdx.x, nblk, mblk, n);
  const int wm = (wave >> 1) * 64, wn = (wave & 1) * 64;
  const int q = lane >> 4, l15 = lane & 15;
  const int lrow = lane >> 3, lcol = lane & 7;
  const int swz = (lcol ^ lrow) * 8;  // B-side: global chunk for LDS slot lcol
  const int xr = l15 & 7;             // read-side row&7
  const int arow = tid >> 1, ahalf = (tid & 1) * 32; // A staging: row, col-half
  const int arx = arow & 7;

  const float* Ag = graphs + (size_t)(mblk * 128) * 8192 + n * 512;
  const __hip_bfloat16* Bg = W1t + (size_t)n * 262144 + (size_t)(nblk * 128) * 512;

  f32x4 acc[4][4] = {};
  for (int ks = 0; ks < 8; ks++) {
    const int k0 = ks * 64;
    // ---- A: 32 fp32 per thread -> cvt -> 4 swizzled ds_write_b128
    const float* asrc = Ag + (size_t)arow * 8192 + k0 + ahalf;
    float f[32];
#pragma unroll
    for (int j = 0; j < 8; j++) *(float4*)(f + j * 4) = *(const float4*)(asrc + j * 4);
    __hip_bfloat16 t[32];
#pragma unroll
    for (int e = 0; e < 32; e++) t[e] = __float2bfloat16(f[e]);
    char* abase = smem + arow * 128;
#pragma unroll
    for (int j = 0; j < 4; j++) {
      int c = (ahalf >> 3) + j; // global chunk index 0..7
      *(bf16x8*)(abase + ((c ^ arx) * 16)) = *(const bf16x8*)(t + j * 8);
    }
    // ---- B: async global->LDS, swizzled on the global side
#pragma unroll
    for (int i = 0; i < 4; i++) {
      const int r = i * 32 + wave * 8 + lrow;
      gl2lds16(Bg + (size_t)r * 512 + k0 + swz,
               smem + 16384 + i * 4096 + wave * 1024 + lane * 16);
    }
    __syncthreads();
#pragma unroll
    for (int hh = 0; hh < 2; hh++) {
      const int co = ((q + hh * 4) ^ xr) * 16;
      bf16x8 av[4], bv[4];
#pragma unroll
      for (int im = 0; im < 4; im++)
        av[im] = *(const bf16x8*)(smem + (wm + im * 16 + l15) * 128 + co);
#pragma unroll
      for (int in = 0; in < 4; in++)
        bv[in] = *(const bf16x8*)(smem + 16384 + (wn + in * 16 + l15) * 128 + co);
#pragma unroll
      for (int im = 0; im < 4; im++)
#pragma unroll
        for (int in = 0; in < 4; in++)
          acc[im][in] = __builtin_amdgcn_mfma_f32_16x16x32_bf16(av[im], bv[in], acc[im][in], 0, 0, 0);
    }
    __syncthreads();
  }

  // epilogue: bias + relu, repack via LDS (row stride 72 elems), coalesced store
  float bias[4];
#pragma unroll
  for (int in = 0; in < 4; in++)
    bias[in] = b1[n * 512 + nblk * 128 + wn + in * 16 + l15];
  char* epi = smem + wave * 9216;
#pragma unroll
  for (int im = 0; im < 4; im++)
#pragma unroll
    for (int in = 0; in < 4; in++)
#pragma unroll
      for (int r = 0; r < 4; r++) {
        float v = acc[im][in][r] + bias[in];
        v = fmaxf(v, 0.f);
        int rl = im * 16 + q * 4 + r;
        int cl = in * 16 + l15;
        *(__hip_bfloat16*)(epi + rl * 144 + cl * 2) = __float2bfloat16(v);
      }
  __syncthreads();
  __hip_bfloat16* Hg = h + (size_t)(mblk * 128 + wm) * 8192 + n * 512 + nblk * 128 + wn;
#pragma unroll
  for (int it = 0; it < 8; it++) {
    int rl = it * 8 + (lane >> 3);
    int cl = (lane & 7) * 8;
    bf16x8 v = *(const bf16x8*)(epi + rl * 144 + cl * 2);
    *(bf16x8*)(Hg + (size_t)rl * 8192 + cl) = v;
  }
}

// ---------------- GEMM2 + weighted combine (fp32 out) -----------------------
__global__ __launch_bounds__(256, 4) void gemm2_kernel(
    const __hip_bfloat16* __restrict__ hbuf,
    const __hip_bfloat16* __restrict__ W2t,
    const float* __restrict__ b2,
    const float* __restrict__ probs,
    float* __restrict__ out) {
  __shared__ char smem[32768];
  const int tid = threadIdx.x, lane = tid & 63, wave = tid >> 6;
  int nblk, mblk, n;
  decode_bid(blockIdx.x, nblk, mblk, n);
  const int wm = (wave >> 1) * 64, wn = (wave & 1) * 64;
  const int q = lane >> 4, l15 = lane & 15;
  const int lrow = lane >> 3, lcol = lane & 7;
  const int swz = (lcol ^ lrow) * 8;
  const int xr = l15 & 7;

  const __hip_bfloat16* Ag = hbuf + (size_t)(mblk * 128) * 8192 + n * 512;
  const __hip_bfloat16* Bg = W2t + (size_t)n * 262144 + (size_t)(nblk * 128) * 512;

  f32x4 acc[4][4] = {};
  for (int ks = 0; ks < 8; ks++) {
    const int k0 = ks * 64;
#pragma unroll
    for (int i = 0; i < 4; i++) {
      const int r = i * 32 + wave * 8 + lrow;
      gl2lds16(Ag + (size_t)r * 8192 + k0 + swz, smem + i * 4096 + wave * 1024 + lane * 16);
      gl2lds16(Bg + (size_t)r * 512 + k0 + swz,
               smem + 16384 + i * 4096 + wave * 1024 + lane * 16);
    }
    __syncthreads();
#pragma unroll
    for (int hh = 0; hh < 2; hh++) {
      const int co = ((q + hh * 4) ^ xr) * 16;
      bf16x8 av[4], bv[4];
#pragma unroll
      for (int im = 0; im < 4; im++)
        av[im] = *(const bf16x8*)(smem + (wm + im * 16 + l15) * 128 + co);
#pragma unroll
      for (int in = 0; in < 4; in++)
        bv[in] = *(const bf16x8*)(smem + 16384 + (wn + in * 16 + l15) * 128 + co);
#pragma unroll
      for (int im = 0; im < 4; im++)
#pragma unroll
        for (int in = 0; in < 4; in++)
          acc[im][in] = __builtin_amdgcn_mfma_f32_16x16x32_bf16(av[im], bv[in], acc[im][in], 0, 0, 0);
    }
    __syncthreads();
  }

  // epilogue: (outs + b2) * probs, shfl-reduce over the 16 j-cols,
  // combined[b, 32n + nblk*8 + (wn>>4) + in]
  float bias[4];
#pragma unroll
  for (int in = 0; in < 4; in++)
    bias[in] = b2[n * 512 + nblk * 128 + wn + in * 16 + l15];
  float* comb = (float*)smem; // [128][8] fp32 (staging LDS reused)
#pragma unroll
  for (int im = 0; im < 4; im++)
#pragma unroll
    for (int r = 0; r < 4; r++) {
      int rl = wm + im * 16 + q * 4 + r; // block-local row 0..127
      float pv = probs[(size_t)(mblk * 128 + rl) * 16 + l15];
#pragma unroll
      for (int in = 0; in < 4; in++) {
        float v = (acc[im][in][r] + bias[in]) * pv;
        v += __shfl_xor(v, 1);
        v += __shfl_xor(v, 2);
        v += __shfl_xor(v, 4);
        v += __shfl_xor(v, 8);
        if (l15 == 0) comb[rl * 8 + (wn >> 4) + in] = v;
      }
    }
  __syncthreads();
  if (tid < 128) {
    float4 v0 = *(const float4*)(comb + tid * 8);
    float4 v1 = *(const float4*)(comb + tid * 8 + 4);
    float* orow = out + (size_t)(mblk * 128 + tid) * 512 + n * 32 + nblk * 8;
    *(float4*)orow = v0;
    *(float4*)(orow + 4) = v1;
  }
}

// ---------------------------------------------------------------------------
extern "C" void kernel_launch(void* const* d_in, const int* in_sizes, int n_in,
                              void* d_out, int out_size, void* d_ws, size_t ws_size,
                              hipStream_t stream) {
  const float* graphs = (const float*)d_in[0];
  const float* W1 = (const float*)d_in[1];
  const float* b1 = (const float*)d_in[2];
  const float* W2 = (const float*)d_in[3];
  const float* b2 = (const float*)d_in[4];
  const float* Wg = (const float*)d_in[5];
  const float* bg = (const float*)d_in[6];
  float* out = (float*)d_out;

  char* ws = (char*)d_ws;
  __hip_bfloat16* W1t = (__hip_bfloat16*)(ws + OFF_W1T);
  __hip_bfloat16* W2t = (__hip_bfloat16*)(ws + OFF_W2T);
  __hip_bfloat16* hb  = (__hip_bfloat16*)(ws + OFF_H);
  float* partial = (float*)(ws + OFF_PART);
  float* probs   = (float*)(ws + OFF_PROB);

  transpose_kernel<<<dim3(16, 16, 32), dim3(32, 8), 0, stream>>>(W1, W2, W1t, W2t);
  gating_kernel<<<1024, 256, 0, stream>>>(graphs, Wg, partial);
  softmax_kernel<<<8, 256, 0, stream>>>(partial, bg, probs, out + 2048 * 512);
  gemm1_kernel<<<1024, 256, 0, stream>>>(graphs, W1t, b1, hb);
  gemm2_kernel<<<1024, 256, 0, stream>>>(hb, W2t, b2, probs, out);
}